// Round 10
// baseline (65.546 us; speedup 1.0000x reference)
//
#include <hip/hip_runtime.h>
#include <hip/hip_bf16.h>
#include <stdint.h>

typedef unsigned short u16;
typedef unsigned int   u32;

#define NB   64
#define NN   4096
#define ND   256
#define NTRI 32896   // 256*257/2
#define NSPLIT 4     // n-splits per batch
#define KROWS  1024  // rows per split
#define NCHUNK 8     // chunks per split (128 rows each)

// ---------- helpers ----------
__device__ __forceinline__ u32 cvtpk(float lo, float hi) {
  u32 r;
  asm("v_cvt_pk_bf16_f32 %0, %1, %2" : "=v"(r) : "v"(lo), "v"(hi));
  return r;
}
__device__ __forceinline__ float b2f_lo(u32 v) {
  union { u32 u; float f; } x; x.u = v << 16; return x.f;
}
__device__ __forceinline__ float b2f_hi(u32 v) {
  union { u32 u; float f; } x; x.u = v & 0xffff0000u; return x.f;
}

typedef __attribute__((ext_vector_type(8))) __bf16 bf16x8;
typedef __attribute__((ext_vector_type(4))) float  f32x4;

// ---------- fused: fp32 stream -> bf16 LDS transpose -> MFMA SYRK ----------
// grid = NB*NSPLIT = 256 blocks, 768 thr (12 waves).
// 128-row chunks (8 per split): half the rendezvous count of the 64-row
// version. Staging waves (0..7) each own 16 rows/chunk, converted in two
// 8-row halves sharing one q-register set (VGPR peak ~160).
__global__ __launch_bounds__(768) void k_cov(const float* __restrict__ in,
                                             u16* __restrict__ covp,
                                             float* __restrict__ part) {
  __shared__ alignas(16) u16 Lt[2][4][256][32];   // 128 KB (2 buffers x 4 planes)
  __shared__ float msum[8][256];                  // 8 KB

  int blk = blockIdx.x;
  int b = blk >> 2, s = blk & 3;
  int t = threadIdx.x;
  int w = t >> 6, lane = t & 63;

  // compute roles: 12 waves = 3 triu tiles x 4 quadrants of 64x64
  int tsel = w >> 2;               // 0:(0,0) 1:(0,1) 2:(1,1)
  int quad = w & 3;
  int wr = quad >> 1, wc = quad & 1;
  int ti = (tsel == 2) ? 1 : 0;
  int tj = (tsel == 0) ? 0 : 1;
  bool diag = (ti == tj);
  bool alive = !(diag && quad == 2);   // (1,0) quadrant of diag tile: redundant
  int fr = lane & 15, fg = lane >> 4;
  int dpA = ti * 128 + wr * 64;
  int dpB = tj * 128 + wc * 64;

  // frag byte offsets within a [256][32] plane (16 KB)
  int aoffB[4], boffB[4];
  int jj = (fg ^ (fr >> 2)) << 4;
#pragma unroll
  for (int m = 0; m < 4; ++m) aoffB[m] = (dpA + m * 16 + fr) * 64 + jj;
#pragma unroll
  for (int n = 0; n < 4; ++n) boffB[n] = (dpB + n * 16 + fr) * 64 + jj;

  // staging roles (waves 0..7): wave w covers chunk rows w*16..w*16+15
  bool stager = (w < 8);
  int c4 = lane;                   // d-quad owned during cvt (rows d=4*c4+e)
  int ksw = w >> 1;                // plane this wave fills (0..3)
  int xw = (w & 1) * 2;            // base 16B n-chunk within plane (+h)

  f32x4 acc[4][4];
  f32x4 zero = {0.f, 0.f, 0.f, 0.f};
#pragma unroll
  for (int m = 0; m < 4; ++m)
#pragma unroll
    for (int n = 0; n < 4; ++n) acc[m][n] = zero;

  const float4* in4 = (const float4*)(in + (size_t)b * NN * ND);
  int rbase0 = (s * KROWS + w * 16) * 64 + c4;  // float4 index of chunk-0 row0

  float4 ms = make_float4(0.f, 0.f, 0.f, 0.f);
  float4 s0, s1, s2, s3, s4, s5, s6, s7;        // rows 0-7 of the 16
  float4 s8, s9, s10, s11, s12, s13, s14, s15;  // rows 8-15

#define ISSUE(C)                                                   \
  if (stager && (C) < NCHUNK) {                                    \
    int rb = rbase0 + (C) * 8192;                                  \
    s0  = in4[rb + 0 * 64];  s1  = in4[rb + 1 * 64];               \
    s2  = in4[rb + 2 * 64];  s3  = in4[rb + 3 * 64];               \
    s4  = in4[rb + 4 * 64];  s5  = in4[rb + 5 * 64];               \
    s6  = in4[rb + 6 * 64];  s7  = in4[rb + 7 * 64];               \
    s8  = in4[rb + 8 * 64];  s9  = in4[rb + 9 * 64];               \
    s10 = in4[rb + 10 * 64]; s11 = in4[rb + 11 * 64];              \
    s12 = in4[rb + 12 * 64]; s13 = in4[rb + 13 * 64];              \
    s14 = in4[rb + 14 * 64]; s15 = in4[rb + 15 * 64];              \
  }

// convert one 8-row half (r0..r7) and write 4x uint4 to plane ksw, chunk x=xw+H
#define CVT_WRITE_H(BUF, H, r0, r1, r2, r3, r4, r5, r6, r7)                   \
  if (stager) {                                                               \
    ms.x += r0.x + r1.x + r2.x + r3.x + r4.x + r5.x + r6.x + r7.x;            \
    ms.y += r0.y + r1.y + r2.y + r3.y + r4.y + r5.y + r6.y + r7.y;            \
    ms.z += r0.z + r1.z + r2.z + r3.z + r4.z + r5.z + r6.z + r7.z;            \
    ms.w += r0.w + r1.w + r2.w + r3.w + r4.w + r5.w + r6.w + r7.w;            \
    int ph = (((xw + (H)) ^ (c4 & 3)) << 4);                                  \
    char* pl = (char*)&Lt[BUF][ksw][0][0] + ph;                               \
    *(uint4*)(pl + (c4 * 4 + 0) * 64) =                                       \
      make_uint4(cvtpk(r0.x, r1.x), cvtpk(r2.x, r3.x),                        \
                 cvtpk(r4.x, r5.x), cvtpk(r6.x, r7.x));                       \
    *(uint4*)(pl + (c4 * 4 + 1) * 64) =                                       \
      make_uint4(cvtpk(r0.y, r1.y), cvtpk(r2.y, r3.y),                        \
                 cvtpk(r4.y, r5.y), cvtpk(r6.y, r7.y));                       \
    *(uint4*)(pl + (c4 * 4 + 2) * 64) =                                       \
      make_uint4(cvtpk(r0.z, r1.z), cvtpk(r2.z, r3.z),                        \
                 cvtpk(r4.z, r5.z), cvtpk(r6.z, r7.z));                       \
    *(uint4*)(pl + (c4 * 4 + 3) * 64) =                                       \
      make_uint4(cvtpk(r0.w, r1.w), cvtpk(r2.w, r3.w),                        \
                 cvtpk(r4.w, r5.w), cvtpk(r6.w, r7.w));                       \
  }

#define CVT_WRITE(BUF)                                                        \
  CVT_WRITE_H(BUF, 0, s0, s1, s2, s3, s4, s5, s6, s7);                        \
  CVT_WRITE_H(BUF, 1, s8, s9, s10, s11, s12, s13, s14, s15);

#define COMPUTE(BUF)                                                          \
  if (alive) {                                                                \
    _Pragma("unroll")                                                         \
    for (int ks = 0; ks < 4; ++ks) {                                          \
      const char* pl = (const char*)&Lt[BUF][ks][0][0];                       \
      bf16x8 af[4], bfv[4];                                                   \
      _Pragma("unroll")                                                       \
      for (int m = 0; m < 4; ++m) af[m] = *(const bf16x8*)(pl + aoffB[m]);    \
      _Pragma("unroll")                                                       \
      for (int n = 0; n < 4; ++n) bfv[n] = *(const bf16x8*)(pl + boffB[n]);   \
      _Pragma("unroll")                                                       \
      for (int m = 0; m < 4; ++m)                                             \
        _Pragma("unroll")                                                     \
        for (int n = 0; n < 4; ++n)                                           \
          acc[m][n] = __builtin_amdgcn_mfma_f32_16x16x32_bf16(                \
              af[m], bfv[n], acc[m][n], 0, 0, 0);                             \
    }                                                                         \
  }

  // prologue: stage chunk 0, issue chunk 1
  ISSUE(0);
  CVT_WRITE(0);
  ISSUE(1);
  __syncthreads();
  // steady state: one barrier per 128-row chunk; loads 2 ahead
  for (int c = 0; c < NCHUNK - 1; ++c) {
    CVT_WRITE((c + 1) & 1);     // chunk c+1
    ISSUE(c + 2);
    COMPUTE(c & 1);
    __syncthreads();
  }
  COMPUTE((NCHUNK - 1) & 1);    // final chunk

  // mean partials: reduce 8 staging waves' column sums -> part[(b*4+s)][256]
  if (stager) *(float4*)&msum[w][c4 * 4] = ms;
  __syncthreads();
  if (t < 256) {
    float m = 0.f;
#pragma unroll
    for (int q = 0; q < 8; ++q) m += msum[q][t];
    part[(size_t)(b * 4 + s) * 256 + t] = m;      // raw sum (k_fin divides)
  }

  // covariance partial: bf16, col-major [lj][li] (li fastest) per tile.
  if (alive) {
    u16* cp = covp + ((size_t)(s * 192 + b * 3 + tsel) << 14);
#pragma unroll
    for (int m = 0; m < 4; ++m) {
      int liB = wr * 64 + m * 16 + fg * 4;
#pragma unroll
      for (int n = 0; n < 4; ++n) {
        int lj = wc * 64 + n * 16 + fr;
        uint2 pk;
        pk.x = cvtpk(acc[m][n][0], acc[m][n][1]);
        pk.y = cvtpk(acc[m][n][2], acc[m][n][3]);
        *(uint2*)(cp + lj * 128 + liB) = pk;
      }
    }
  }
#undef ISSUE
#undef CVT_WRITE_H
#undef CVT_WRITE
#undef COMPUTE
}

// ---------- k_fin: coalesced col-major reads -> LDS transpose -> row-major
// triu writes. grid = 192 tiles x 2 halves = 384 blocks, 256 thr.
__global__ __launch_bounds__(256) void k_fin(const u16* __restrict__ covp,
                                             const float* __restrict__ part,
                                             float* __restrict__ out) {
  __shared__ float mean_s[256];
  __shared__ float Lf[64][130];          // half-tile transposed, +2 pad
  int blk = blockIdx.x;
  int tile = blk >> 1, half = blk & 1;   // tile = b*3 + tsel
  int b = tile / 3, tsel = tile % 3;
  int ti = (tsel == 2) ? 1 : 0;
  int tj = (tsel == 0) ? 0 : 1;
  bool dtile = (ti == tj);
  int t = threadIdx.x;

  float m = 0.f;
#pragma unroll
  for (int q = 0; q < NSPLIT; ++q) m += part[(size_t)(b * 4 + q) * 256 + t];
  mean_s[t] = m * (1.f / 4096.f);

  const u32* cp0 = (const u32*)(covp + ((size_t)(0 * 192 + tile) << 14));
  const u32* cp1 = (const u32*)(covp + ((size_t)(1 * 192 + tile) << 14));
  const u32* cp2 = (const u32*)(covp + ((size_t)(2 * 192 + tile) << 14));
  const u32* cp3 = (const u32*)(covp + ((size_t)(3 * 192 + tile) << 14));

  // phase 1: read col-major (coalesced u32), sum splits, transpose into LDS.
  // covp u32 index = lj*64 + li2 (li2 = half*32 + li2h).
#pragma unroll 4
  for (int k = 0; k < 16; ++k) {
    int idx  = k * 256 + t;              // 0..4095 over [lj 0..127][li2h 0..31]
    int li2h = idx & 31, lj = idx >> 5;
    if (dtile && lj < half * 64 + li2h * 2) continue;  // fully-dead u32 pair
    int e2 = lj * 64 + half * 32 + li2h;
    u32 v0 = cp0[e2], v1 = cp1[e2], v2 = cp2[e2], v3 = cp3[e2];
    Lf[li2h * 2 + 0][lj] = b2f_lo(v0) + b2f_lo(v1) + b2f_lo(v2) + b2f_lo(v3);
    Lf[li2h * 2 + 1][lj] = b2f_hi(v0) + b2f_hi(v1) + b2f_hi(v2) + b2f_hi(v3);
  }
  __syncthreads();

  // phase 2: row-major writes, contiguous 256B per wave-instruction.
  const float inv = 1.f / 4096.f;
  float* ob = out + (size_t)b * NTRI;
#pragma unroll 4
  for (int e0 = 0; e0 < 8192; e0 += 256) {
    int e = e0 + t;
    int ll = e >> 7, lj = e & 127;       // row within half, col
    int i = ti * 128 + half * 64 + ll;
    int j = tj * 128 + lj;
    if (j >= i) {
      int ro = i * 256 - ((i * (i - 1)) >> 1) - i;
      ob[ro + j] = Lf[ll][lj] * inv - mean_s[i] * mean_s[j];
    }
  }
}

// ---------- fallback: fp32 vector SYRK, no workspace ----------
__global__ __launch_bounds__(256) void k_cov_f32(const float* __restrict__ in,
                                                 float* __restrict__ out) {
  int blk = blockIdx.x;
  int b = blk / 10, ts = blk % 10;
  int ti, tj;
  if (ts < 4)      { ti = 0; tj = ts; }
  else if (ts < 7) { ti = 1; tj = ts - 3; }
  else if (ts < 9) { ti = 2; tj = ts - 5; }
  else             { ti = 3; tj = 3; }
  bool diag = (ti == tj);

  __shared__ float Pa[32][68];
  __shared__ float Pb[32][68];
  __shared__ float smA[64], smB[64];
  int t = threadIdx.x;
  if (t < 64) { smA[t] = 0.f; smB[t] = 0.f; }
  float acc[4][4] = {};
  int ri = t >> 4, rj = t & 15;
  const float* base = in + (size_t)b * NN * ND;

  for (int ks = 0; ks < 128; ++ks) {
    int nk = ks * 32;
    __syncthreads();
    for (int cc = t; cc < 512; cc += 256) {
      int r = cc >> 4, c4 = (cc & 15) << 2;
      *(float4*)&Pa[r][c4] = *(const float4*)(base + (size_t)(nk + r) * ND + ti * 64 + c4);
      if (!diag)
        *(float4*)&Pb[r][c4] = *(const float4*)(base + (size_t)(nk + r) * ND + tj * 64 + c4);
    }
    __syncthreads();
    if (t < 64) {
      float s = 0.f;
      for (int r = 0; r < 32; ++r) s += Pa[r][t];
      smA[t] += s;
    } else if (!diag && t < 128) {
      float s = 0.f;
      for (int r = 0; r < 32; ++r) s += Pb[r][t - 64];
      smB[t - 64] += s;
    }
    float(*Pbb)[68] = diag ? Pa : Pb;
    for (int k = 0; k < 32; ++k) {
      float4 a = *(const float4*)&Pa[k][ri << 2];
      float4 v = *(const float4*)&Pbb[k][rj << 2];
      float av[4] = {a.x, a.y, a.z, a.w};
      float bv[4] = {v.x, v.y, v.z, v.w};
#pragma unroll
      for (int e = 0; e < 4; ++e)
#pragma unroll
        for (int f = 0; f < 4; ++f) acc[e][f] += av[e] * bv[f];
    }
  }
  __syncthreads();
  const float inv = 1.f / 4096.f;
  const float* mB = diag ? smA : smB;
#pragma unroll
  for (int e = 0; e < 4; ++e) {
    int i = ti * 64 + (ri << 2) + e;
    float mi = smA[(ri << 2) + e] * inv;
    int ro = i * 256 - ((i * (i - 1)) >> 1) - i;
#pragma unroll
    for (int f = 0; f < 4; ++f) {
      int j = tj * 64 + (rj << 2) + f;
      if (j >= i)
        out[(size_t)b * NTRI + ro + j] = acc[e][f] * inv - mi * mB[(rj << 2) + f] * inv;
    }
  }
}

// ---------- launch ----------
extern "C" void kernel_launch(void* const* d_in, const int* in_sizes, int n_in,
                              void* d_out, int out_size, void* d_ws, size_t ws_size,
                              hipStream_t stream) {
  const float* in = (const float*)d_in[0];
  float* out = (float*)d_out;

  const size_t COVP_B = (size_t)NSPLIT * 192 * 16384 * 2;   // 25,165,824 (bf16)
  const size_t PART_B = (size_t)NB * NSPLIT * 256 * 4;      //     262,144
  const size_t need = COVP_B + PART_B;

  if (ws_size >= need) {
    u16*   covp = (u16*)d_ws;
    float* part = (float*)((char*)d_ws + COVP_B);
    k_cov<<<NB * NSPLIT, 768, 0, stream>>>(in, covp, part);
    k_fin<<<NB * 3 * 2, 256, 0, stream>>>(covp, part, out);
  } else {
    k_cov_f32<<<NB * 10, 256, 0, stream>>>(in, out);
  }
}

// Round 11
// 64.198 us; speedup vs baseline: 1.0210x; 1.0210x over previous
//
#include <hip/hip_runtime.h>
#include <hip/hip_bf16.h>
#include <stdint.h>

typedef unsigned short u16;
typedef unsigned int   u32;

#define NB   64
#define NN   4096
#define ND   256
#define NTRI 32896   // 256*257/2
#define NSPLIT 4     // n-splits per batch
#define KROWS  1024  // rows per split
#define NCHUNK 16    // chunks per split (64 rows each)

// ---------- helpers ----------
__device__ __forceinline__ u32 cvtpk(float lo, float hi) {
  u32 r;
  asm("v_cvt_pk_bf16_f32 %0, %1, %2" : "=v"(r) : "v"(lo), "v"(hi));
  return r;
}
__device__ __forceinline__ float b2f_lo(u32 v) {
  union { u32 u; float f; } x; x.u = v << 16; return x.f;
}
__device__ __forceinline__ float b2f_hi(u32 v) {
  union { u32 u; float f; } x; x.u = v & 0xffff0000u; return x.f;
}

typedef __attribute__((ext_vector_type(8))) __bf16 bf16x8;
typedef __attribute__((ext_vector_type(4))) float  f32x4;

// ---------- fused: fp32 stream -> bf16 LDS transpose -> MFMA SYRK ----------
// grid = NB*NSPLIT = 256 blocks, 768 thr (12 waves). Round-9 structure
// (64-row chunks, 64KB LDS, proven 61.3us).
// covp partials stored BF16, col-major [lj][li] per 128x128 tile.
__global__ __launch_bounds__(768) void k_cov(const float* __restrict__ in,
                                             u16* __restrict__ covp,
                                             float* __restrict__ part) {
  __shared__ alignas(16) u16 Lt[2][2][256][32];   // 64 KB (2 buffers)
  __shared__ float msum[8][256];                  // 8 KB

  int blk = blockIdx.x;
  int b = blk >> 2, s = blk & 3;
  int t = threadIdx.x;
  int w = t >> 6, lane = t & 63;

  // compute roles: 12 waves = 3 triu tiles x 4 quadrants of 64x64
  int tsel = w >> 2;               // 0:(0,0) 1:(0,1) 2:(1,1)
  int quad = w & 3;
  int wr = quad >> 1, wc = quad & 1;
  int ti = (tsel == 2) ? 1 : 0;
  int tj = (tsel == 0) ? 0 : 1;
  bool diag = (ti == tj);
  bool alive = !(diag && quad == 2);   // (1,0) quadrant of diag tile: redundant
  int fr = lane & 15, fg = lane >> 4;
  int dpA = ti * 128 + wr * 64;
  int dpB = tj * 128 + wc * 64;

  // frag byte offsets within a [256][32] plane (16 KB)
  int aoffB[4], boffB[4];
  int jj = (fg ^ (fr >> 2)) << 4;
#pragma unroll
  for (int m = 0; m < 4; ++m) aoffB[m] = (dpA + m * 16 + fr) * 64 + jj;
#pragma unroll
  for (int n = 0; n < 4; ++n) boffB[n] = (dpB + n * 16 + fr) * 64 + jj;

  // staging roles (waves 0..7): wave w covers n_local rows w*8..w*8+7
  bool stager = (w < 8);
  int c4 = lane;                   // d-quad owned during cvt (rows d=4*c4+e)
  int ksw = w >> 2;                // ks-plane this wave fills (0/1)
  int xw = w & 3;                  // 16B n-chunk within plane
  int swz = ((xw ^ (c4 & 3)) << 4);

  f32x4 acc[4][4];
  f32x4 zero = {0.f, 0.f, 0.f, 0.f};
#pragma unroll
  for (int m = 0; m < 4; ++m)
#pragma unroll
    for (int n = 0; n < 4; ++n) acc[m][n] = zero;

  const float4* in4 = (const float4*)(in + (size_t)b * NN * ND);
  int rbase0 = (s * KROWS + w * 8) * 64 + c4;   // float4 index of chunk-0 row0

  float4 ms = make_float4(0.f, 0.f, 0.f, 0.f);
  float4 s0, s1, s2, s3, s4, s5, s6, s7;        // fp32 staging (1 set)
  uint4 q0, q1, q2, q3;                         // converted bf16 (1 set)

#define ISSUE(C)                                                \
  if (stager && (C) < NCHUNK) {                                 \
    int rb = rbase0 + (C) * 4096;                               \
    s0 = in4[rb + 0 * 64]; s1 = in4[rb + 1 * 64];               \
    s2 = in4[rb + 2 * 64]; s3 = in4[rb + 3 * 64];               \
    s4 = in4[rb + 4 * 64]; s5 = in4[rb + 5 * 64];               \
    s6 = in4[rb + 6 * 64]; s7 = in4[rb + 7 * 64];               \
  }

#define CVT()                                                                 \
  if (stager) {                                                               \
    ms.x += s0.x + s1.x + s2.x + s3.x + s4.x + s5.x + s6.x + s7.x;            \
    ms.y += s0.y + s1.y + s2.y + s3.y + s4.y + s5.y + s6.y + s7.y;            \
    ms.z += s0.z + s1.z + s2.z + s3.z + s4.z + s5.z + s6.z + s7.z;            \
    ms.w += s0.w + s1.w + s2.w + s3.w + s4.w + s5.w + s6.w + s7.w;            \
    q0 = make_uint4(cvtpk(s0.x, s1.x), cvtpk(s2.x, s3.x),                     \
                    cvtpk(s4.x, s5.x), cvtpk(s6.x, s7.x));                    \
    q1 = make_uint4(cvtpk(s0.y, s1.y), cvtpk(s2.y, s3.y),                     \
                    cvtpk(s4.y, s5.y), cvtpk(s6.y, s7.y));                    \
    q2 = make_uint4(cvtpk(s0.z, s1.z), cvtpk(s2.z, s3.z),                     \
                    cvtpk(s4.z, s5.z), cvtpk(s6.z, s7.z));                    \
    q3 = make_uint4(cvtpk(s0.w, s1.w), cvtpk(s2.w, s3.w),                     \
                    cvtpk(s4.w, s5.w), cvtpk(s6.w, s7.w));                    \
  }

#define WRITE(BUF)                                                            \
  if (stager) {                                                               \
    char* pl = (char*)&Lt[BUF][ksw][0][0] + swz;                              \
    *(uint4*)(pl + (c4 * 4 + 0) * 64) = q0;                                   \
    *(uint4*)(pl + (c4 * 4 + 1) * 64) = q1;                                   \
    *(uint4*)(pl + (c4 * 4 + 2) * 64) = q2;                                   \
    *(uint4*)(pl + (c4 * 4 + 3) * 64) = q3;                                   \
  }

#define COMPUTE(BUF)                                                          \
  if (alive) {                                                                \
    _Pragma("unroll")                                                         \
    for (int ks = 0; ks < 2; ++ks) {                                          \
      const char* pl = (const char*)&Lt[BUF][ks][0][0];                       \
      bf16x8 af[4], bfv[4];                                                   \
      _Pragma("unroll")                                                       \
      for (int m = 0; m < 4; ++m) af[m] = *(const bf16x8*)(pl + aoffB[m]);    \
      _Pragma("unroll")                                                       \
      for (int n = 0; n < 4; ++n) bfv[n] = *(const bf16x8*)(pl + boffB[n]);   \
      _Pragma("unroll")                                                       \
      for (int m = 0; m < 4; ++m)                                             \
        _Pragma("unroll")                                                     \
        for (int n = 0; n < 4; ++n)                                           \
          acc[m][n] = __builtin_amdgcn_mfma_f32_16x16x32_bf16(                \
              af[m], bfv[n], acc[m][n], 0, 0, 0);                             \
    }                                                                         \
  }

  // prologue: stage chunk 0, issue chunk 1
  ISSUE(0);
  CVT();
  ISSUE(1);
  WRITE(0);
  __syncthreads();
  // steady state: one barrier per chunk; loads 2 ahead
  for (int c = 0; c < NCHUNK - 1; ++c) {
    CVT();                      // chunk c+1
    ISSUE(c + 2);
    WRITE((c + 1) & 1);
    COMPUTE(c & 1);
    __syncthreads();
  }
  COMPUTE((NCHUNK - 1) & 1);    // final chunk

  // mean partials: reduce 8 staging waves' column sums -> part[(b*4+s)][256]
  if (stager) *(float4*)&msum[w][c4 * 4] = ms;
  __syncthreads();
  if (t < 256) {
    float m = 0.f;
#pragma unroll
    for (int q = 0; q < 8; ++q) m += msum[q][t];
    part[(size_t)(b * 4 + s) * 256 + t] = m;      // raw sum (k_fin divides)
  }

  // covariance partial: bf16, col-major [lj][li] (li fastest) per tile.
  if (alive) {
    u16* cp = covp + ((size_t)(s * 192 + b * 3 + tsel) << 14);
#pragma unroll
    for (int m = 0; m < 4; ++m) {
      int liB = wr * 64 + m * 16 + fg * 4;
#pragma unroll
      for (int n = 0; n < 4; ++n) {
        int lj = wc * 64 + n * 16 + fr;
        uint2 pk;
        pk.x = cvtpk(acc[m][n][0], acc[m][n][1]);
        pk.y = cvtpk(acc[m][n][2], acc[m][n][3]);
        *(uint2*)(cp + lj * 128 + liB) = pk;
      }
    }
  }
#undef ISSUE
#undef CVT
#undef WRITE
#undef COMPUTE
}

// ---------- k_fin: coalesced col-major reads -> LDS transpose -> row-major
// triu writes. grid = 192 tiles x 2 halves = 384 blocks, 256 thr.
__global__ __launch_bounds__(256) void k_fin(const u16* __restrict__ covp,
                                             const float* __restrict__ part,
                                             float* __restrict__ out) {
  __shared__ float mean_s[256];
  __shared__ float Lf[64][130];          // half-tile transposed, +2 pad
  int blk = blockIdx.x;
  int tile = blk >> 1, half = blk & 1;   // tile = b*3 + tsel
  int b = tile / 3, tsel = tile % 3;
  int ti = (tsel == 2) ? 1 : 0;
  int tj = (tsel == 0) ? 0 : 1;
  bool dtile = (ti == tj);
  int t = threadIdx.x;

  float m = 0.f;
#pragma unroll
  for (int q = 0; q < NSPLIT; ++q) m += part[(size_t)(b * 4 + q) * 256 + t];
  mean_s[t] = m * (1.f / 4096.f);

  const u32* cp0 = (const u32*)(covp + ((size_t)(0 * 192 + tile) << 14));
  const u32* cp1 = (const u32*)(covp + ((size_t)(1 * 192 + tile) << 14));
  const u32* cp2 = (const u32*)(covp + ((size_t)(2 * 192 + tile) << 14));
  const u32* cp3 = (const u32*)(covp + ((size_t)(3 * 192 + tile) << 14));

  // phase 1: read col-major (coalesced u32), sum splits, transpose into LDS.
  // covp u32 index = lj*64 + li2 (li2 = half*32 + li2h).
#pragma unroll 4
  for (int k = 0; k < 16; ++k) {
    int idx  = k * 256 + t;              // 0..4095 over [lj 0..127][li2h 0..31]
    int li2h = idx & 31, lj = idx >> 5;
    if (dtile && lj < half * 64 + li2h * 2) continue;  // fully-dead u32 pair
    int e2 = lj * 64 + half * 32 + li2h;
    u32 v0 = cp0[e2], v1 = cp1[e2], v2 = cp2[e2], v3 = cp3[e2];
    Lf[li2h * 2 + 0][lj] = b2f_lo(v0) + b2f_lo(v1) + b2f_lo(v2) + b2f_lo(v3);
    Lf[li2h * 2 + 1][lj] = b2f_hi(v0) + b2f_hi(v1) + b2f_hi(v2) + b2f_hi(v3);
  }
  __syncthreads();

  // phase 2: row-major writes, contiguous 256B per wave-instruction.
  const float inv = 1.f / 4096.f;
  float* ob = out + (size_t)b * NTRI;
#pragma unroll 4
  for (int e0 = 0; e0 < 8192; e0 += 256) {
    int e = e0 + t;
    int ll = e >> 7, lj = e & 127;       // row within half, col
    int i = ti * 128 + half * 64 + ll;
    int j = tj * 128 + lj;
    if (j >= i) {
      int ro = i * 256 - ((i * (i - 1)) >> 1) - i;
      ob[ro + j] = Lf[ll][lj] * inv - mean_s[i] * mean_s[j];
    }
  }
}

// ---------- fallback: fp32 vector SYRK, no workspace ----------
__global__ __launch_bounds__(256) void k_cov_f32(const float* __restrict__ in,
                                                 float* __restrict__ out) {
  int blk = blockIdx.x;
  int b = blk / 10, ts = blk % 10;
  int ti, tj;
  if (ts < 4)      { ti = 0; tj = ts; }
  else if (ts < 7) { ti = 1; tj = ts - 3; }
  else if (ts < 9) { ti = 2; tj = ts - 5; }
  else             { ti = 3; tj = 3; }
  bool diag = (ti == tj);

  __shared__ float Pa[32][68];
  __shared__ float Pb[32][68];
  __shared__ float smA[64], smB[64];
  int t = threadIdx.x;
  if (t < 64) { smA[t] = 0.f; smB[t] = 0.f; }
  float acc[4][4] = {};
  int ri = t >> 4, rj = t & 15;
  const float* base = in + (size_t)b * NN * ND;

  for (int ks = 0; ks < 128; ++ks) {
    int nk = ks * 32;
    __syncthreads();
    for (int cc = t; cc < 512; cc += 256) {
      int r = cc >> 4, c4 = (cc & 15) << 2;
      *(float4*)&Pa[r][c4] = *(const float4*)(base + (size_t)(nk + r) * ND + ti * 64 + c4);
      if (!diag)
        *(float4*)&Pb[r][c4] = *(const float4*)(base + (size_t)(nk + r) * ND + tj * 64 + c4);
    }
    __syncthreads();
    if (t < 64) {
      float s = 0.f;
      for (int r = 0; r < 32; ++r) s += Pa[r][t];
      smA[t] += s;
    } else if (!diag && t < 128) {
      float s = 0.f;
      for (int r = 0; r < 32; ++r) s += Pb[r][t - 64];
      smB[t - 64] += s;
    }
    float(*Pbb)[68] = diag ? Pa : Pb;
    for (int k = 0; k < 32; ++k) {
      float4 a = *(const float4*)&Pa[k][ri << 2];
      float4 v = *(const float4*)&Pbb[k][rj << 2];
      float av[4] = {a.x, a.y, a.z, a.w};
      float bv[4] = {v.x, v.y, v.z, v.w};
#pragma unroll
      for (int e = 0; e < 4; ++e)
#pragma unroll
        for (int f = 0; f < 4; ++f) acc[e][f] += av[e] * bv[f];
    }
  }
  __syncthreads();
  const float inv = 1.f / 4096.f;
  const float* mB = diag ? smA : smB;
#pragma unroll
  for (int e = 0; e < 4; ++e) {
    int i = ti * 64 + (ri << 2) + e;
    float mi = smA[(ri << 2) + e] * inv;
    int ro = i * 256 - ((i * (i - 1)) >> 1) - i;
#pragma unroll
    for (int f = 0; f < 4; ++f) {
      int j = tj * 64 + (rj << 2) + f;
      if (j >= i)
        out[(size_t)b * NTRI + ro + j] = acc[e][f] * inv - mi * mB[(rj << 2) + f] * inv;
    }
  }
}

// ---------- launch ----------
extern "C" void kernel_launch(void* const* d_in, const int* in_sizes, int n_in,
                              void* d_out, int out_size, void* d_ws, size_t ws_size,
                              hipStream_t stream) {
  const float* in = (const float*)d_in[0];
  float* out = (float*)d_out;

  const size_t COVP_B = (size_t)NSPLIT * 192 * 16384 * 2;   // 25,165,824 (bf16)
  const size_t PART_B = (size_t)NB * NSPLIT * 256 * 4;      //     262,144
  const size_t need = COVP_B + PART_B;

  if (ws_size >= need) {
    u16*   covp = (u16*)d_ws;
    float* part = (float*)((char*)d_ws + COVP_B);
    k_cov<<<NB * NSPLIT, 768, 0, stream>>>(in, covp, part);
    k_fin<<<NB * 3 * 2, 256, 0, stream>>>(covp, part, out);
  } else {
    k_cov_f32<<<NB * 10, 256, 0, stream>>>(in, out);
  }
}

// Round 12
// 61.018 us; speedup vs baseline: 1.0742x; 1.0521x over previous
//
#include <hip/hip_runtime.h>
#include <hip/hip_bf16.h>
#include <stdint.h>

typedef unsigned short u16;
typedef unsigned int   u32;

#define NB   64
#define NN   4096
#define ND   256
#define NTRI 32896   // 256*257/2
#define NSPLIT 4     // n-splits per batch
#define KROWS  1024  // rows per split
#define NCHUNK 16    // chunks per split (64 rows each)

// ---------- helpers ----------
__device__ __forceinline__ u32 cvtpk(float lo, float hi) {
  u32 r;
  asm("v_cvt_pk_bf16_f32 %0, %1, %2" : "=v"(r) : "v"(lo), "v"(hi));
  return r;
}
__device__ __forceinline__ float b2f_lo(u32 v) {
  union { u32 u; float f; } x; x.u = v << 16; return x.f;
}
__device__ __forceinline__ float b2f_hi(u32 v) {
  union { u32 u; float f; } x; x.u = v & 0xffff0000u; return x.f;
}

typedef __attribute__((ext_vector_type(8))) __bf16 bf16x8;
typedef __attribute__((ext_vector_type(4))) float  f32x4;

// ---------- fused: fp32 stream -> bf16 LDS transpose -> MFMA SYRK ----------
// grid = NB*NSPLIT = 256 blocks, 768 thr (12 waves). Round-9 structure
// (64-row chunks, 64KB LDS, proven 61.3us).
// covp partials stored BF16, col-major [lj][li] per 128x128 tile.
__global__ __launch_bounds__(768) void k_cov(const float* __restrict__ in,
                                             u16* __restrict__ covp,
                                             float* __restrict__ part) {
  __shared__ alignas(16) u16 Lt[2][2][256][32];   // 64 KB (2 buffers)
  __shared__ float msum[8][256];                  // 8 KB

  int blk = blockIdx.x;
  int b = blk >> 2, s = blk & 3;
  int t = threadIdx.x;
  int w = t >> 6, lane = t & 63;

  // compute roles: 12 waves = 3 triu tiles x 4 quadrants of 64x64
  int tsel = w >> 2;               // 0:(0,0) 1:(0,1) 2:(1,1)
  int quad = w & 3;
  int wr = quad >> 1, wc = quad & 1;
  int ti = (tsel == 2) ? 1 : 0;
  int tj = (tsel == 0) ? 0 : 1;
  bool diag = (ti == tj);
  bool alive = !(diag && quad == 2);   // (1,0) quadrant of diag tile: redundant
  int fr = lane & 15, fg = lane >> 4;
  int dpA = ti * 128 + wr * 64;
  int dpB = tj * 128 + wc * 64;

  // frag byte offsets within a [256][32] plane (16 KB)
  int aoffB[4], boffB[4];
  int jj = (fg ^ (fr >> 2)) << 4;
#pragma unroll
  for (int m = 0; m < 4; ++m) aoffB[m] = (dpA + m * 16 + fr) * 64 + jj;
#pragma unroll
  for (int n = 0; n < 4; ++n) boffB[n] = (dpB + n * 16 + fr) * 64 + jj;

  // staging roles (waves 0..7): wave w covers n_local rows w*8..w*8+7
  bool stager = (w < 8);
  int c4 = lane;                   // d-quad owned during cvt (rows d=4*c4+e)
  int ksw = w >> 2;                // ks-plane this wave fills (0/1)
  int xw = w & 3;                  // 16B n-chunk within plane
  int swz = ((xw ^ (c4 & 3)) << 4);

  f32x4 acc[4][4];
  f32x4 zero = {0.f, 0.f, 0.f, 0.f};
#pragma unroll
  for (int m = 0; m < 4; ++m)
#pragma unroll
    for (int n = 0; n < 4; ++n) acc[m][n] = zero;

  const float4* in4 = (const float4*)(in + (size_t)b * NN * ND);
  int rbase0 = (s * KROWS + w * 8) * 64 + c4;   // float4 index of chunk-0 row0

  float4 ms = make_float4(0.f, 0.f, 0.f, 0.f);
  float4 s0, s1, s2, s3, s4, s5, s6, s7;        // fp32 staging (1 set)
  uint4 q0, q1, q2, q3;                         // converted bf16 (1 set)

#define ISSUE(C)                                                \
  if (stager && (C) < NCHUNK) {                                 \
    int rb = rbase0 + (C) * 4096;                               \
    s0 = in4[rb + 0 * 64]; s1 = in4[rb + 1 * 64];               \
    s2 = in4[rb + 2 * 64]; s3 = in4[rb + 3 * 64];               \
    s4 = in4[rb + 4 * 64]; s5 = in4[rb + 5 * 64];               \
    s6 = in4[rb + 6 * 64]; s7 = in4[rb + 7 * 64];               \
  }

#define CVT()                                                                 \
  if (stager) {                                                               \
    ms.x += s0.x + s1.x + s2.x + s3.x + s4.x + s5.x + s6.x + s7.x;            \
    ms.y += s0.y + s1.y + s2.y + s3.y + s4.y + s5.y + s6.y + s7.y;            \
    ms.z += s0.z + s1.z + s2.z + s3.z + s4.z + s5.z + s6.z + s7.z;            \
    ms.w += s0.w + s1.w + s2.w + s3.w + s4.w + s5.w + s6.w + s7.w;            \
    q0 = make_uint4(cvtpk(s0.x, s1.x), cvtpk(s2.x, s3.x),                     \
                    cvtpk(s4.x, s5.x), cvtpk(s6.x, s7.x));                    \
    q1 = make_uint4(cvtpk(s0.y, s1.y), cvtpk(s2.y, s3.y),                     \
                    cvtpk(s4.y, s5.y), cvtpk(s6.y, s7.y));                    \
    q2 = make_uint4(cvtpk(s0.z, s1.z), cvtpk(s2.z, s3.z),                     \
                    cvtpk(s4.z, s5.z), cvtpk(s6.z, s7.z));                    \
    q3 = make_uint4(cvtpk(s0.w, s1.w), cvtpk(s2.w, s3.w),                     \
                    cvtpk(s4.w, s5.w), cvtpk(s6.w, s7.w));                    \
  }

#define WRITE(BUF)                                                            \
  if (stager) {                                                               \
    char* pl = (char*)&Lt[BUF][ksw][0][0] + swz;                              \
    *(uint4*)(pl + (c4 * 4 + 0) * 64) = q0;                                   \
    *(uint4*)(pl + (c4 * 4 + 1) * 64) = q1;                                   \
    *(uint4*)(pl + (c4 * 4 + 2) * 64) = q2;                                   \
    *(uint4*)(pl + (c4 * 4 + 3) * 64) = q3;                                   \
  }

#define COMPUTE(BUF)                                                          \
  if (alive) {                                                                \
    _Pragma("unroll")                                                         \
    for (int ks = 0; ks < 2; ++ks) {                                          \
      const char* pl = (const char*)&Lt[BUF][ks][0][0];                       \
      bf16x8 af[4], bfv[4];                                                   \
      _Pragma("unroll")                                                       \
      for (int m = 0; m < 4; ++m) af[m] = *(const bf16x8*)(pl + aoffB[m]);    \
      _Pragma("unroll")                                                       \
      for (int n = 0; n < 4; ++n) bfv[n] = *(const bf16x8*)(pl + boffB[n]);   \
      _Pragma("unroll")                                                       \
      for (int m = 0; m < 4; ++m)                                             \
        _Pragma("unroll")                                                     \
        for (int n = 0; n < 4; ++n)                                           \
          acc[m][n] = __builtin_amdgcn_mfma_f32_16x16x32_bf16(                \
              af[m], bfv[n], acc[m][n], 0, 0, 0);                             \
    }                                                                         \
  }

  // prologue: stage chunk 0, issue chunk 1
  ISSUE(0);
  CVT();
  ISSUE(1);
  WRITE(0);
  __syncthreads();
  // steady state: one barrier per chunk; loads 2 ahead
  for (int c = 0; c < NCHUNK - 1; ++c) {
    CVT();                      // chunk c+1
    ISSUE(c + 2);
    WRITE((c + 1) & 1);
    COMPUTE(c & 1);
    __syncthreads();
  }
  COMPUTE((NCHUNK - 1) & 1);    // final chunk

  // mean partials: reduce 8 staging waves' column sums -> part[(b*4+s)][256]
  if (stager) *(float4*)&msum[w][c4 * 4] = ms;
  __syncthreads();
  if (t < 256) {
    float m = 0.f;
#pragma unroll
    for (int q = 0; q < 8; ++q) m += msum[q][t];
    part[(size_t)(b * 4 + s) * 256 + t] = m;      // raw sum (k_fin divides)
  }

  // covariance partial: bf16, col-major [lj][li] (li fastest) per tile.
  if (alive) {
    u16* cp = covp + ((size_t)(s * 192 + b * 3 + tsel) << 14);
#pragma unroll
    for (int m = 0; m < 4; ++m) {
      int liB = wr * 64 + m * 16 + fg * 4;
#pragma unroll
      for (int n = 0; n < 4; ++n) {
        int lj = wc * 64 + n * 16 + fr;
        uint2 pk;
        pk.x = cvtpk(acc[m][n][0], acc[m][n][1]);
        pk.y = cvtpk(acc[m][n][2], acc[m][n][3]);
        *(uint2*)(cp + lj * 128 + liB) = pk;
      }
    }
  }
#undef ISSUE
#undef CVT
#undef WRITE
#undef COMPUTE
}

// ---------- k_fin: coalesced col-major reads -> LDS transpose -> row-major
// triu writes. grid = 192 tiles x 2 halves = 384 blocks, 256 thr.
// NOTE: no below-diagonal read-skip — r11 measured it as a 3us REGRESSION
// (divergent continue breaks load batching; skipped reads were L3-hits).
__global__ __launch_bounds__(256) void k_fin(const u16* __restrict__ covp,
                                             const float* __restrict__ part,
                                             float* __restrict__ out) {
  __shared__ float mean_s[256];
  __shared__ float Lf[64][130];          // half-tile transposed, +2 pad
  int blk = blockIdx.x;
  int tile = blk >> 1, half = blk & 1;   // tile = b*3 + tsel
  int b = tile / 3, tsel = tile % 3;
  int ti = (tsel == 2) ? 1 : 0;
  int tj = (tsel == 0) ? 0 : 1;
  int t = threadIdx.x;

  float m = 0.f;
#pragma unroll
  for (int q = 0; q < NSPLIT; ++q) m += part[(size_t)(b * 4 + q) * 256 + t];
  mean_s[t] = m * (1.f / 4096.f);

  const u32* cp0 = (const u32*)(covp + ((size_t)(0 * 192 + tile) << 14));
  const u32* cp1 = (const u32*)(covp + ((size_t)(1 * 192 + tile) << 14));
  const u32* cp2 = (const u32*)(covp + ((size_t)(2 * 192 + tile) << 14));
  const u32* cp3 = (const u32*)(covp + ((size_t)(3 * 192 + tile) << 14));

  // phase 1: read col-major (coalesced u32), sum splits, transpose into LDS.
  // covp u32 index = lj*64 + li2 (li2 = half*32 + li2h).
#pragma unroll 4
  for (int k = 0; k < 16; ++k) {
    int idx  = k * 256 + t;              // 0..4095 over [lj 0..127][li2h 0..31]
    int li2h = idx & 31, lj = idx >> 5;
    int e2 = lj * 64 + half * 32 + li2h;
    u32 v0 = cp0[e2], v1 = cp1[e2], v2 = cp2[e2], v3 = cp3[e2];
    Lf[li2h * 2 + 0][lj] = b2f_lo(v0) + b2f_lo(v1) + b2f_lo(v2) + b2f_lo(v3);
    Lf[li2h * 2 + 1][lj] = b2f_hi(v0) + b2f_hi(v1) + b2f_hi(v2) + b2f_hi(v3);
  }
  __syncthreads();

  // phase 2: row-major writes, contiguous 256B per wave-instruction.
  const float inv = 1.f / 4096.f;
  float* ob = out + (size_t)b * NTRI;
#pragma unroll 4
  for (int e0 = 0; e0 < 8192; e0 += 256) {
    int e = e0 + t;
    int ll = e >> 7, lj = e & 127;       // row within half, col
    int i = ti * 128 + half * 64 + ll;
    int j = tj * 128 + lj;
    if (j >= i) {
      int ro = i * 256 - ((i * (i - 1)) >> 1) - i;
      ob[ro + j] = Lf[ll][lj] * inv - mean_s[i] * mean_s[j];
    }
  }
}

// ---------- fallback: fp32 vector SYRK, no workspace ----------
__global__ __launch_bounds__(256) void k_cov_f32(const float* __restrict__ in,
                                                 float* __restrict__ out) {
  int blk = blockIdx.x;
  int b = blk / 10, ts = blk % 10;
  int ti, tj;
  if (ts < 4)      { ti = 0; tj = ts; }
  else if (ts < 7) { ti = 1; tj = ts - 3; }
  else if (ts < 9) { ti = 2; tj = ts - 5; }
  else             { ti = 3; tj = 3; }
  bool diag = (ti == tj);

  __shared__ float Pa[32][68];
  __shared__ float Pb[32][68];
  __shared__ float smA[64], smB[64];
  int t = threadIdx.x;
  if (t < 64) { smA[t] = 0.f; smB[t] = 0.f; }
  float acc[4][4] = {};
  int ri = t >> 4, rj = t & 15;
  const float* base = in + (size_t)b * NN * ND;

  for (int ks = 0; ks < 128; ++ks) {
    int nk = ks * 32;
    __syncthreads();
    for (int cc = t; cc < 512; cc += 256) {
      int r = cc >> 4, c4 = (cc & 15) << 2;
      *(float4*)&Pa[r][c4] = *(const float4*)(base + (size_t)(nk + r) * ND + ti * 64 + c4);
      if (!diag)
        *(float4*)&Pb[r][c4] = *(const float4*)(base + (size_t)(nk + r) * ND + tj * 64 + c4);
    }
    __syncthreads();
    if (t < 64) {
      float s = 0.f;
      for (int r = 0; r < 32; ++r) s += Pa[r][t];
      smA[t] += s;
    } else if (!diag && t < 128) {
      float s = 0.f;
      for (int r = 0; r < 32; ++r) s += Pb[r][t - 64];
      smB[t - 64] += s;
    }
    float(*Pbb)[68] = diag ? Pa : Pb;
    for (int k = 0; k < 32; ++k) {
      float4 a = *(const float4*)&Pa[k][ri << 2];
      float4 v = *(const float4*)&Pbb[k][rj << 2];
      float av[4] = {a.x, a.y, a.z, a.w};
      float bv[4] = {v.x, v.y, v.z, v.w};
#pragma unroll
      for (int e = 0; e < 4; ++e)
#pragma unroll
        for (int f = 0; f < 4; ++f) acc[e][f] += av[e] * bv[f];
    }
  }
  __syncthreads();
  const float inv = 1.f / 4096.f;
  const float* mB = diag ? smA : smB;
#pragma unroll
  for (int e = 0; e < 4; ++e) {
    int i = ti * 64 + (ri << 2) + e;
    float mi = smA[(ri << 2) + e] * inv;
    int ro = i * 256 - ((i * (i - 1)) >> 1) - i;
#pragma unroll
    for (int f = 0; f < 4; ++f) {
      int j = tj * 64 + (rj << 2) + f;
      if (j >= i)
        out[(size_t)b * NTRI + ro + j] = acc[e][f] * inv - mi * mB[(rj << 2) + f] * inv;
    }
  }
}

// ---------- launch ----------
extern "C" void kernel_launch(void* const* d_in, const int* in_sizes, int n_in,
                              void* d_out, int out_size, void* d_ws, size_t ws_size,
                              hipStream_t stream) {
  const float* in = (const float*)d_in[0];
  float* out = (float*)d_out;

  const size_t COVP_B = (size_t)NSPLIT * 192 * 16384 * 2;   // 25,165,824 (bf16)
  const size_t PART_B = (size_t)NB * NSPLIT * 256 * 4;      //     262,144
  const size_t need = COVP_B + PART_B;

  if (ws_size >= need) {
    u16*   covp = (u16*)d_ws;
    float* part = (float*)((char*)d_ws + COVP_B);
    k_cov<<<NB * NSPLIT, 768, 0, stream>>>(in, covp, part);
    k_fin<<<NB * 3 * 2, 256, 0, stream>>>(covp, part, out);
  } else {
    k_cov_f32<<<NB * 10, 256, 0, stream>>>(in, out);
  }
}